// Round 4
// baseline (138.161 us; speedup 1.0000x reference)
//
#include <hip/hip_runtime.h>

typedef __attribute__((ext_vector_type(8))) short short8v;
typedef __attribute__((ext_vector_type(4))) float float4v;

constexpr int BB = 64, SS = 512, HH = 768, LL = 9, NCHUNK = 16, CHUNK = 32;
constexpr int KSTEPS = 24, KHALF = 12;

// ---------------------------------------------------------------------------
// Single fused kernel. Block (b,c) of 256 threads (4 waves):
//   0. Stage W into LDS as per-(kstep,lane) bf16 MFMA A-fragments (L2-hot).
//   1. Emissions for its 32 positions via MFMA, K split across wave pairs
//      (wave 0+2 -> tile 0, wave 1+3 -> tile 1; each 12 k-steps), f32 partial
//      accs reduced through LDS -> emLDS[32][9].
//   2. Waves 0-1: barrier-free 9x9 log-semiring chunk product (ds_bpermute
//      row broadcasts), c==0 carries alpha0 in row 0. -> chunkM global.
//      Wave 2: interior numerator terms -> atomicAdd(numAcc[b]).
//   3. Fan-in: per-batch ticket; 16th block folds the batch's 16 matrices
//      -> partials[b]; 64th batch-finisher sums partials -> out[0] (store).
// ---------------------------------------------------------------------------
__global__ __launch_bounds__(256) void fused_all(
    const float* __restrict__ hs, const int* __restrict__ mask,
    const int* __restrict__ labels, const float* __restrict__ W,
    const float* __restrict__ bias, const float* __restrict__ st,
    const float* __restrict__ et, const float* __restrict__ trans,
    float* __restrict__ chunkM, float* __restrict__ partials,
    float* __restrict__ numAcc, int* __restrict__ batchctr,
    int* __restrict__ globalctr, float* __restrict__ out) {
  const int bc = blockIdx.x, b = bc >> 4, c = bc & 15;
  const int tid = threadIdx.x, wave = tid >> 6, lane = tid & 63;
  const int rc = lane & 15, kb = lane >> 4;

  __shared__ unsigned short WF[KSTEPS * 512];  // 24 KB bf16 A-fragments
  __shared__ float emLDS[CHUNK * LL];
  __shared__ float4v pacc[2][64];
  __shared__ int tickLDS;

  // ---- phase 0: stage W fragments into LDS ----
  for (int idx = tid; idx < KSTEPS * 512; idx += 256) {
    int s = idx >> 9, r = idx & 511, ln = r >> 3, e = r & 7;
    int lbl = ln & 15, kblk = ln >> 4;
    float f = (lbl < LL) ? W[(size_t)(s * 32 + kblk * 8 + e) * LL + lbl] : 0.f;
    WF[idx] = (unsigned short)(__float_as_uint(f) >> 16);
  }
  __syncthreads();

  // ---- phase 1: emissions tile via MFMA, K-split ----
  const int tile = wave & 1, khalf = wave >> 1;
  const int posg = b * SS + c * CHUNK + tile * 16;
  const float* aptr = hs + (size_t)(posg + rc) * HH + khalf * (KHALF * 32) + kb * 8;
  const short8v* wf =
      reinterpret_cast<const short8v*>(WF) + (size_t)(khalf * KHALF) * 64 + lane;

  float4v acc = {0.f, 0.f, 0.f, 0.f};
#pragma unroll
  for (int s = 0; s < KHALF; ++s) {
    float4 a0 = *reinterpret_cast<const float4*>(aptr + s * 32);
    float4 a1 = *reinterpret_cast<const float4*>(aptr + s * 32 + 4);
    union { unsigned u[4]; short8v v; } Bf;
    Bf.u[0] = __builtin_amdgcn_perm(__float_as_uint(a0.y), __float_as_uint(a0.x), 0x07060302u);
    Bf.u[1] = __builtin_amdgcn_perm(__float_as_uint(a0.w), __float_as_uint(a0.z), 0x07060302u);
    Bf.u[2] = __builtin_amdgcn_perm(__float_as_uint(a1.y), __float_as_uint(a1.x), 0x07060302u);
    Bf.u[3] = __builtin_amdgcn_perm(__float_as_uint(a1.w), __float_as_uint(a1.z), 0x07060302u);
    short8v Af = wf[(size_t)s * 64];
    acc = __builtin_amdgcn_mfma_f32_16x16x32_bf16(Af, Bf.v, acc, 0, 0, 0);
  }
  if (wave >= 2) pacc[wave - 2][lane] = acc;
  __syncthreads();
  if (wave < 2) {
    float4v o = pacc[wave][lane];
    if (kb < 3) {
#pragma unroll
      for (int r = 0; r < 4; ++r) {
        int lbl = kb * 4 + r;  // D row = label
        if (lbl < LL)
          emLDS[(tile * 16 + rc) * LL + lbl] = acc[r] + o[r] + bias[lbl];
      }
    }
  }
  __syncthreads();

  // ---- phase 2: chunk log-semiring product (waves 0-1) / numerator (wave 2)
  const int* mkp = mask + b * SS + c * CHUNK;
  if (wave < 2) {
    bool valid;
    int q;
    if (wave == 0) { valid = lane < 63; q = valid ? lane : 0; }
    else           { valid = lane < 18; q = valid ? 63 + lane : 0; }
    const int i = q / 9, j = q % 9;
    const int rowbase = lane - j;

    int addr[9];
#pragma unroll
    for (int k = 0; k < 9; ++k) addr[k] = (rowbase + k) * 4;
    float tc[9];
#pragma unroll
    for (int k = 0; k < 9; ++k) tc[k] = trans[k * LL + j];
    float ev[CHUNK];
#pragma unroll
    for (int s = 0; s < CHUNK; ++s) ev[s] = emLDS[s * LL + j];
    int mv[CHUNK];
#pragma unroll
    for (int s = 0; s < CHUNK; ++s) mv[s] = mkp[s];

    float mij;
    if (c == 0 && i == 0) mij = st[j] + emLDS[j];
    else                  mij = (i == j) ? 0.f : -1e30f;

#pragma unroll
    for (int s = 0; s < CHUNK; ++s) {
      float x[9];
      float m = -3e38f;
#pragma unroll
      for (int k = 0; k < 9; ++k) {
        x[k] = __int_as_float(
                   __builtin_amdgcn_ds_bpermute(addr[k], __float_as_int(mij))) +
               tc[k];
        m = fmaxf(m, x[k]);
      }
      float s2 = 0.f;
#pragma unroll
      for (int k = 0; k < 9; ++k) s2 += __expf(x[k] - m);
      float nxt = m + __logf(s2) + ev[s];
      bool apply = valid && (mv[s] != 0) && !(c == 0 && s == 0);
      mij = apply ? nxt : mij;
    }
    if (valid) chunkM[(size_t)bc * 81 + q] = mij;
  } else if (wave == 2) {
    float val = 0.f;
    if (lane < CHUNK) {
      const int* lab = labels + b * SS;
      int tg = c * CHUNK + lane;
      if (tg >= 1 && mkp[lane] != 0) {
        int lp = lab[tg - 1], lc = lab[tg];
        val = trans[lp * LL + lc] + emLDS[lane * LL + lc];
      }
      if (c == 0 && lane == 0) {
        int l0 = lab[0];
        val += st[l0] + emLDS[l0];
      }
    }
#pragma unroll
    for (int off = 32; off; off >>= 1) val += __shfl_xor(val, off);
    if (lane == 0) atomicAdd(numAcc + b, val);
  }

  // ---- phase 3: fan-in ----
  __threadfence();
  __syncthreads();
  if (tid == 0) tickLDS = atomicAdd(batchctr + b, 1);
  __syncthreads();
  if (tickLDS == NCHUNK - 1 && wave == 0) {
    __threadfence();  // acquire: see all 16 blocks' chunkM/numAcc
    const float* Mb = chunkM + (size_t)b * NCHUNK * 81;

    float v = (lane < LL) ? Mb[lane] : 0.f;  // alpha after chunk 0 (row 0)
    for (int cc = 1; cc < NCHUNK; ++cc) {
      const float* M = Mb + cc * 81;
      float vk[9];
#pragma unroll
      for (int k = 0; k < 9; ++k) vk[k] = __shfl(v, k);
      if (lane < LL) {
        float x[9];
        float m = -3e38f;
#pragma unroll
        for (int k = 0; k < 9; ++k) {
          x[k] = vk[k] + M[k * 9 + lane];
          m = fmaxf(m, x[k]);
        }
        float s = 0.f;
#pragma unroll
        for (int k = 0; k < 9; ++k) s += __expf(x[k] - m);
        v = m + __logf(s);
      }
    }

    float vj[9];
#pragma unroll
    for (int k = 0; k < 9; ++k) vj[k] = __shfl(v, k) + et[k];
    float m = -3e38f;
#pragma unroll
    for (int k = 0; k < 9; ++k) m = fmaxf(m, vj[k]);
    float s = 0.f;
#pragma unroll
    for (int k = 0; k < 9; ++k) s += __expf(vj[k] - m);
    float denom = m + __logf(s);

    const int* mk = mask + b * SS;
    int cnt = 0;
    for (int tt = lane; tt < SS; tt += 64) cnt += mk[tt];
#pragma unroll
    for (int off = 32; off; off >>= 1) cnt += __shfl_xor(cnt, off);

    int g = 0;
    if (lane == 0) {
      float etterm = et[labels[b * SS + cnt - 1]];
      partials[b] = denom - etterm - numAcc[b];
      __threadfence();
      g = atomicAdd(globalctr, 1);
    }
    g = __shfl(g, 0);
    if (g == BB - 1) {  // last batch to finish: reduce partials -> out
      __threadfence();
      float p = partials[lane];
#pragma unroll
      for (int off = 32; off; off >>= 1) p += __shfl_xor(p, off);
      if (lane == 0) out[0] = p;
    }
  }
}

extern "C" void kernel_launch(void* const* d_in, const int* in_sizes, int n_in,
                              void* d_out, int out_size, void* d_ws, size_t ws_size,
                              hipStream_t stream) {
  const float* hs     = (const float*)d_in[0];
  const int*   mask   = (const int*)d_in[1];
  const int*   labels = (const int*)d_in[2];
  const float* W      = (const float*)d_in[3];
  const float* bias   = (const float*)d_in[4];
  const float* st     = (const float*)d_in[5];
  const float* et     = (const float*)d_in[6];
  const float* trans  = (const float*)d_in[7];

  float* chunkM   = (float*)d_ws;                       // 82944 f32
  float* partials = chunkM + (size_t)BB * NCHUNK * 81;  // 64 f32
  float* numAcc   = partials + BB;                      // 64 f32 (zeroed)
  int*   batchctr = (int*)(numAcc + BB);                // 64 i32 (zeroed)
  int*   globalctr= batchctr + BB;                      // 1 i32 (zeroed)
  float* out      = (float*)d_out;

  hipMemsetAsync(numAcc, 0, (BB + BB + 1) * 4, stream);
  fused_all<<<BB * NCHUNK, 256, 0, stream>>>(hs, mask, labels, W, bias, st, et,
                                             trans, chunkM, partials, numAcc,
                                             batchctr, globalctr, out);
}

// Round 5
// 49.755 us; speedup vs baseline: 2.7768x; 2.7768x over previous
//
#include <hip/hip_runtime.h>

typedef __attribute__((ext_vector_type(8))) short short8v;
typedef __attribute__((ext_vector_type(4))) float float4v;

constexpr int BB = 64, SS = 512, HH = 768, LL = 9, NCHUNK = 16, CHUNK = 32;
constexpr int KSTEPS = 24, KHALF = 12;

// ---------------------------------------------------------------------------
// Kernel 0: pack W^T into per-(kstep,lane) bf16 MFMA A-fragments (global, L2).
// Also zeroes numAcc[0..63] and out[0].
// ---------------------------------------------------------------------------
__global__ __launch_bounds__(64) void packW_kernel(
    const float* __restrict__ W, unsigned short* __restrict__ packedW,
    float* __restrict__ numAcc, float* __restrict__ out) {
  const int s = blockIdx.x;      // kstep 0..23
  const int l = threadIdx.x;     // lane 0..63
  const int label = l & 15;
  const int kb = l >> 4;
  union { unsigned short u[8]; short8v v; } P;
#pragma unroll
  for (int e = 0; e < 8; ++e) {
    int k = s * 32 + kb * 8 + e;
    float f = (label < LL) ? W[(size_t)k * LL + label] : 0.f;
    P.u[e] = (unsigned short)(__float_as_uint(f) >> 16);
  }
  *reinterpret_cast<short8v*>(packedW + ((size_t)(s * 64 + l)) * 8) = P.v;
  if (s == 0) {
    if (l < BB) numAcc[l] = 0.f;
    if (l == 0) out[0] = 0.f;
  }
}

// ---------------------------------------------------------------------------
// Kernel 1 (fused): per (b,c) block of 256 threads (4 waves):
//   1. Emissions for its 32 positions via MFMA. K split across wave pairs:
//      wave = tile + 2*khalf; each wave does 12 k-steps of one 16-pos tile,
//      loads issued in 2 batches of 18 (deep pipeline, one vmcnt wait each).
//      f32 partial accs reduced through LDS -> emLDS[32][9].
//   2. Waves 0-1: barrier-free 9x9 log-semiring chunk product (ds_bpermute
//      row broadcasts), c==0 carries alpha0 in row 0 -> chunkM global.
//      Wave 2: interior numerator terms -> atomicAdd(numAcc[b]).
// ---------------------------------------------------------------------------
__global__ __launch_bounds__(256, 4) void fused_kernel(
    const float* __restrict__ hs, const int* __restrict__ mask,
    const int* __restrict__ labels, const unsigned short* __restrict__ packedW,
    const float* __restrict__ bias, const float* __restrict__ st,
    const float* __restrict__ trans, float* __restrict__ chunkM,
    float* __restrict__ numAcc) {
  const int bc = blockIdx.x;
  const int b = bc >> 4;
  const int c = bc & 15;
  const int tid = threadIdx.x;
  const int wave = tid >> 6;
  const int lane = tid & 63;
  const int rc = lane & 15;
  const int kb = lane >> 4;

  __shared__ float emLDS[CHUNK * LL];
  __shared__ float4v pacc[2][64];

  // ---- phase 1: emissions tile via MFMA, K-split, batched loads ----
  const int tile = wave & 1, khalf = wave >> 1;
  const int posg = b * SS + c * CHUNK + tile * 16;
  const float4* ap = reinterpret_cast<const float4*>(hs + (size_t)(posg + rc) * HH) +
                     khalf * (KHALF * 8) + kb * 2;
  const short8v* pw = reinterpret_cast<const short8v*>(packedW) +
                      (size_t)(khalf * KHALF) * 64 + lane;

  float4v acc = {0.f, 0.f, 0.f, 0.f};
#pragma unroll
  for (int g = 0; g < 2; ++g) {
    float4 A0[6], A1[6];
    short8v Wf[6];
#pragma unroll
    for (int s = 0; s < 6; ++s) {
      int ks = g * 6 + s;
      A0[s] = ap[ks * 8];
      A1[s] = ap[ks * 8 + 1];
      Wf[s] = pw[(size_t)ks * 64];
    }
#pragma unroll
    for (int s = 0; s < 6; ++s) {
      union { unsigned u[4]; short8v v; } Bf;
      Bf.u[0] = __builtin_amdgcn_perm(__float_as_uint(A0[s].y), __float_as_uint(A0[s].x), 0x07060302u);
      Bf.u[1] = __builtin_amdgcn_perm(__float_as_uint(A0[s].w), __float_as_uint(A0[s].z), 0x07060302u);
      Bf.u[2] = __builtin_amdgcn_perm(__float_as_uint(A1[s].y), __float_as_uint(A1[s].x), 0x07060302u);
      Bf.u[3] = __builtin_amdgcn_perm(__float_as_uint(A1[s].w), __float_as_uint(A1[s].z), 0x07060302u);
      acc = __builtin_amdgcn_mfma_f32_16x16x32_bf16(Wf[s], Bf.v, acc, 0, 0, 0);
    }
  }
  if (wave >= 2) pacc[wave - 2][lane] = acc;
  __syncthreads();
  if (wave < 2) {
    float4v o = pacc[wave][lane];
    if (kb < 3) {
#pragma unroll
      for (int r = 0; r < 4; ++r) {
        int lbl = kb * 4 + r;  // D row = label
        if (lbl < LL)
          emLDS[(tile * 16 + rc) * LL + lbl] = acc[r] + o[r] + bias[lbl];
      }
    }
  }
  __syncthreads();

  // ---- phase 2: chunk log-semiring product (waves 0-1) / numerator (wave 2)
  const int* mkp = mask + b * SS + c * CHUNK;
  if (wave < 2) {
    bool valid;
    int q;
    if (wave == 0) { valid = lane < 63; q = valid ? lane : 0; }
    else           { valid = lane < 18; q = valid ? 63 + lane : 0; }
    const int i = q / 9, j = q % 9;
    const int rowbase = lane - j;

    int addr[9];
#pragma unroll
    for (int k = 0; k < 9; ++k) addr[k] = (rowbase + k) * 4;
    float tc[9];
#pragma unroll
    for (int k = 0; k < 9; ++k) tc[k] = trans[k * LL + j];
    float ev[CHUNK];
#pragma unroll
    for (int s = 0; s < CHUNK; ++s) ev[s] = emLDS[s * LL + j];
    int mv[CHUNK];
#pragma unroll
    for (int s = 0; s < CHUNK; ++s) mv[s] = mkp[s];

    float mij;
    if (c == 0 && i == 0) mij = st[j] + emLDS[j];        // alpha0[j]
    else                  mij = (i == j) ? 0.f : -1e30f; // identity row

#pragma unroll
    for (int s = 0; s < CHUNK; ++s) {
      float x[9];
      float m = -3e38f;
#pragma unroll
      for (int k = 0; k < 9; ++k) {
        x[k] = __int_as_float(
                   __builtin_amdgcn_ds_bpermute(addr[k], __float_as_int(mij))) +
               tc[k];
        m = fmaxf(m, x[k]);
      }
      float s2 = 0.f;
#pragma unroll
      for (int k = 0; k < 9; ++k) s2 += __expf(x[k] - m);
      float nxt = m + __logf(s2) + ev[s];
      bool apply = valid && (mv[s] != 0) && !(c == 0 && s == 0);
      mij = apply ? nxt : mij;
    }
    if (valid) chunkM[(size_t)bc * 81 + q] = mij;
  } else if (wave == 2) {
    float val = 0.f;
    if (lane < CHUNK) {
      const int* lab = labels + b * SS;
      int tg = c * CHUNK + lane;
      if (tg >= 1 && mkp[lane] != 0) {
        int lp = lab[tg - 1], lc = lab[tg];
        val = trans[lp * LL + lc] + emLDS[lane * LL + lc];
      }
      if (c == 0 && lane == 0) {
        int l0 = lab[0];
        val += st[l0] + emLDS[l0];
      }
    }
#pragma unroll
    for (int off = 32; off; off >>= 1) val += __shfl_xor(val, off);
    if (lane == 0) atomicAdd(numAcc + b, val);
  }
}

// ---------------------------------------------------------------------------
// Kernel 2: per batch: v = chunkM[b][0].row0 (alpha after chunk 0), fold 15
// matrices, denom = lse(v + end_trans); out += denom - end_term - numAcc[b].
// ---------------------------------------------------------------------------
__global__ __launch_bounds__(64) void final_kernel(
    const int* __restrict__ mask, const int* __restrict__ labels,
    const float* __restrict__ et, const float* __restrict__ chunkM,
    const float* __restrict__ numAcc, float* __restrict__ out) {
  const int b = blockIdx.x;
  const int lane = threadIdx.x;
  const float* Mb = chunkM + (size_t)b * NCHUNK * 81;

  float v = (lane < LL) ? Mb[lane] : 0.f;  // row 0 of chunk 0
  for (int c = 1; c < NCHUNK; ++c) {
    const float* M = Mb + c * 81;
    float vk[9];
#pragma unroll
    for (int k = 0; k < 9; ++k) vk[k] = __shfl(v, k);
    if (lane < LL) {
      float x[9];
      float m = -3e38f;
#pragma unroll
      for (int k = 0; k < 9; ++k) {
        x[k] = vk[k] + M[k * 9 + lane];
        m = fmaxf(m, x[k]);
      }
      float s = 0.f;
#pragma unroll
      for (int k = 0; k < 9; ++k) s += __expf(x[k] - m);
      v = m + __logf(s);
    }
  }

  float vj[9];
#pragma unroll
  for (int k = 0; k < 9; ++k) vj[k] = __shfl(v, k) + et[k];
  float m = -3e38f;
#pragma unroll
  for (int k = 0; k < 9; ++k) m = fmaxf(m, vj[k]);
  float s = 0.f;
#pragma unroll
  for (int k = 0; k < 9; ++k) s += __expf(vj[k] - m);
  float denom = m + __logf(s);

  const int* mk = mask + b * SS;
  int cnt = 0;
  for (int tt = lane; tt < SS; tt += 64) cnt += mk[tt];
#pragma unroll
  for (int off = 32; off; off >>= 1) cnt += __shfl_xor(cnt, off);

  if (lane == 0) {
    int last = cnt - 1;
    float etterm = et[labels[b * SS + last]];
    atomicAdd(out, denom - etterm - numAcc[b]);
  }
}

extern "C" void kernel_launch(void* const* d_in, const int* in_sizes, int n_in,
                              void* d_out, int out_size, void* d_ws, size_t ws_size,
                              hipStream_t stream) {
  const float* hs     = (const float*)d_in[0];
  const int*   mask   = (const int*)d_in[1];
  const int*   labels = (const int*)d_in[2];
  const float* W      = (const float*)d_in[3];
  const float* bias   = (const float*)d_in[4];
  const float* st     = (const float*)d_in[5];
  const float* et     = (const float*)d_in[6];
  const float* trans  = (const float*)d_in[7];

  float* chunkM = (float*)d_ws;                                  // 82944 f32
  unsigned short* packedW =
      (unsigned short*)(chunkM + (size_t)BB * NCHUNK * 81);      // 24*64*8 bf16
  float* numAcc = (float*)(packedW + (size_t)KSTEPS * 64 * 8);   // 64 f32
  float* out    = (float*)d_out;

  packW_kernel<<<KSTEPS, 64, 0, stream>>>(W, packedW, numAcc, out);
  fused_kernel<<<BB * NCHUNK, 256, 0, stream>>>(hs, mask, labels, packedW,
                                                bias, st, trans, chunkM, numAcc);
  final_kernel<<<BB, 64, 0, stream>>>(mask, labels, et, chunkM, numAcc, out);
}